// Round 2
// baseline (105.610 us; speedup 1.0000x reference)
//
#include <hip/hip_runtime.h>
#include <hip/hip_bf16.h>
#include <math.h>

// Problem constants
#define Hn 256
#define Nn 64
#define Bn 4
#define Ln 2048
#define NC 32      // chunks per sequence

typedef __attribute__((ext_vector_type(8))) short short8;
typedef __attribute__((ext_vector_type(4))) float f32x4;

#define MFMA16 __builtin_amdgcn_mfma_f32_16x16x32_bf16

__device__ inline short bf16hi(float x) {
    union { __hip_bfloat16 b; unsigned short u; } cv;
    cv.b = __float2bfloat16(x);
    return (short)cv.u;
}
__device__ inline float bf16f(short s) {
    union { __hip_bfloat16 b; unsigned short u; } cv;
    cv.u = (unsigned short)s;
    return __bfloat162float(cv.b);
}

// complex square in place
#define CSQ(r, i) { float _nr = (r)*(r) - (i)*(i); (i) = 2.f*(r)*(i); (r) = _nr; }

// ---------------------------------------------------------------------------
// K1: one block per (b,h). Fuses column-gather, per-h precompute (duplicated
// across the 4 b-blocks of each h; fragments go straight to registers), MFMA
// chunk-scan, GELU. D*u is folded into the Toeplitz diagonal (Krow[0] += D),
// so u is read exactly once. No uT / AF1 / AF2 / apar workspace round-trips.
// LDS phases (all sequential, one 36 KB buffer):
//   us[32*68]f (8.7 KB) -> shA[2][64][66]f (33.8 KB) + cbrL/kb
//   -> P2[64][35][2]f (17.9 KB) + Sb[2][2][32][72]s (18.4 KB) -> Yl
// ---------------------------------------------------------------------------
__global__ __launch_bounds__(256, 4)
void k_s4d(const float* __restrict__ u,
           const float* __restrict__ lnr, const float* __restrict__ imv,
           const float* __restrict__ Bre, const float* __restrict__ Bim,
           const float* __restrict__ Cre, const float* __restrict__ Cim,
           const float* __restrict__ lstep, const float* __restrict__ Dp,
           float* __restrict__ ypre)
{
    __shared__ __align__(16) char smem[36864];

    const int bh   = blockIdx.x;
    const int b    = bh >> 8;
    const int h    = bh & (Hn - 1);
    const int tid  = threadIdx.x;
    const int lane = tid & 63;
    const int w    = __builtin_amdgcn_readfirstlane(tid >> 6);
    const int l15  = lane & 15;
    const int kq   = lane >> 4;
    const int mrow = (w << 4) + l15;

    // ---- P0: gather u[b,:,h] into padded LDS (us[c*68 + t], 2-way banks) ----
    float* us = (float*)smem;           // 32*68 = 2176 floats (8704 B)
    {
        const float* ucol = u + (size_t)b * Ln * Hn + h;
        #pragma unroll
        for (int i = 0; i < 8; ++i) {
            int l = tid + (i << 8);
            us[(l >> 6) * 68 + (l & 63)] = ucol[(size_t)l * Hn];
        }
    }

    // ---- per-lane (n = lane) parameters, duplicated across waves ----
    float st  = fminf(fmaxf(expf(lstep[h]), 1e-5f), 1.0f);
    float lam = -expf(lnr[lane]);
    float er  = expf(st * lam);
    float smv = st * imv[lane];
    float ar  = er * cosf(smv);
    float ai  = er * sinf(smv);
    float bre = Bre[h * Nn + lane] * st;
    float bim = Bim[h * Nn + lane] * st;
    float crr = Cre[h * Nn + lane];
    float cii = Cim[h * Nn + lane];
    float cbr = crr * bre - cii * bim;
    float cbi = crr * bim + cii * bre;
    float Dval = Dp[h];

    // power ladder: a^16, a^32, a^48, a^64
    float a16r = ar, a16i = ai;
    CSQ(a16r, a16i); CSQ(a16r, a16i); CSQ(a16r, a16i); CSQ(a16r, a16i);
    float a32r = a16r, a32i = a16i; CSQ(a32r, a32i);
    float a48r = a32r * a16r - a32i * a16i;
    float a48i = a32r * a16i + a32i * a16r;
    float a64r = a32r, a64i = a32i; CSQ(a64r, a64i);

    __syncthreads();

    // ---- U fragments from us (bf16 hi/lo) ----
    short8 Uh[2][2], Ul[2][2];             // [kt][ct]
    #pragma unroll
    for (int kt = 0; kt < 2; ++kt)
        #pragma unroll
        for (int ct = 0; ct < 2; ++ct) {
            int c = ct * 16 + l15;
            const float* up = &us[c * 68 + kt * 32 + kq * 8];
            float4 f0 = *(const float4*)up;
            float4 f1 = *(const float4*)(up + 4);
            float xv[8] = {f0.x, f0.y, f0.z, f0.w, f1.x, f1.y, f1.z, f1.w};
            union { short s[8]; short8 v; } hh, ll;
            #pragma unroll
            for (int j = 0; j < 8; ++j) {
                short hs = bf16hi(xv[j]);
                hh.s[j] = hs;
                ll.s[j] = bf16hi(xv[j] - bf16f(hs));
            }
            Uh[kt][ct] = hh.v;
            Ul[kt][ct] = ll.v;
        }

    __syncthreads();   // us dead; shA may now overwrite it

    // ---- P1a: Apow[n][t] = a_n^(63-t); wave w covers powers 16w..16w+15 ----
    float (*shA)[64][66] = (float (*)[64][66])smem;   // 33792 B
    float* cbrL = (float*)(smem + 33792);             // 64 f
    float* kb   = (float*)(smem + 34048);             // 128 f
    {
        float pr = 1.f, pi = 0.f;
        if (w == 1)      { pr = a16r; pi = a16i; }
        else if (w == 2) { pr = a32r; pi = a32i; }
        else if (w == 3) { pr = a48r; pi = a48i; }
        for (int i = 0; i < 16; ++i) {
            int t = 63 - ((w << 4) + i);
            shA[0][lane][t] = pr;
            shA[1][lane][t] = pi;
            float nr = pr * ar - pi * ai; pi = pr * ai + pi * ar; pr = nr;
        }
    }
    __syncthreads();

    // A1 fragments straight to registers (producer == consumer thread)
    short8 A1f[2][2];                      // [re/im][kt]
    #pragma unroll
    for (int cm = 0; cm < 2; ++cm)
        #pragma unroll
        for (int kt = 0; kt < 2; ++kt) {
            union { short s[8]; short8 v; } uh;
            #pragma unroll
            for (int j = 0; j < 8; ++j)
                uh.s[j] = bf16hi(shA[cm][mrow][kt * 32 + kq * 8 + j]);
            A1f[cm][kt] = uh.v;
        }
    __syncthreads();

    // ---- P1b: G[j][n] = CB_n a_n^(j+1); wave w covers j = 16w..16w+15 ----
    {
        float Pr, Pi;
        if (w == 0)      { Pr = ar; Pi = ai; }
        else if (w == 1) { Pr = a16r * ar - a16i * ai; Pi = a16r * ai + a16i * ar; }
        else if (w == 2) { Pr = a32r * ar - a32i * ai; Pi = a32r * ai + a32i * ar; }
        else             { Pr = a48r * ar - a48i * ai; Pi = a48r * ai + a48i * ar; }
        if (tid < 64) cbrL[lane] = cbr;
        for (int i = 0; i < 16; ++i) {
            int j = (w << 4) + i;
            shA[0][j][lane] = cbr * Pr - cbi * Pi;
            shA[1][j][lane] = cbr * Pi + cbi * Pr;
            float nr = Pr * ar - Pi * ai; Pi = Pr * ai + Pi * ar; Pr = nr;
        }
    }
    __syncthreads();

    // Krow -> kb (zero-padded low half); D folded into Krow[0] (T diagonal)
    if (tid < 64) kb[tid] = 0.f;
    else if (tid < 128) {
        int t2 = tid - 64;
        float s = 0.f;
        if (t2 == 0) { for (int n2 = 0; n2 < 64; ++n2) s += cbrL[n2]; s += Dval; }
        else         { for (int n2 = 0; n2 < 64; ++n2) s += shA[0][t2 - 1][n2]; }
        kb[tid] = s;
    }
    __syncthreads();

    // A2 fragments: [T | Gre | -Gim] rows mrow, straight to registers
    short8 A2f[6];
    #pragma unroll
    for (int kt = 0; kt < 6; ++kt) {
        union { short s[8]; short8 v; } uh;
        #pragma unroll
        for (int j = 0; j < 8; ++j) {
            float x;
            if (kt < 2) {
                int kk = kt * 32 + kq * 8 + j;           // column m of T
                x = kb[64 + mrow - kk];                   // T[j][m] = Krow[j-m]
            } else {
                int q2 = kt - 2;
                int nn = (q2 & 1) * 32 + kq * 8 + j;
                x = (q2 >> 1) ? -shA[1][mrow][nn] : shA[0][mrow][nn];
            }
            uh.s[j] = bf16hi(x);
        }
        A2f[kt] = uh.v;
    }
    __syncthreads();   // shA/kb dead; P2/Sb may now overwrite

    // ---- set 1: P = Apow * U ----
    f32x4 Pre_acc[2] = {{0.f,0.f,0.f,0.f},{0.f,0.f,0.f,0.f}};
    f32x4 Pim_acc[2] = {{0.f,0.f,0.f,0.f},{0.f,0.f,0.f,0.f}};
    #pragma unroll
    for (int kt = 0; kt < 2; ++kt) {
        #pragma unroll
        for (int ct = 0; ct < 2; ++ct) {
            Pre_acc[ct] = MFMA16(A1f[0][kt], Uh[kt][ct], Pre_acc[ct], 0, 0, 0);
            Pre_acc[ct] = MFMA16(A1f[0][kt], Ul[kt][ct], Pre_acc[ct], 0, 0, 0);
            Pim_acc[ct] = MFMA16(A1f[1][kt], Uh[kt][ct], Pim_acc[ct], 0, 0, 0);
            Pim_acc[ct] = MFMA16(A1f[1][kt], Ul[kt][ct], Pim_acc[ct], 0, 0, 0);
        }
    }
    float (*P2)[35][2]     = (float (*)[35][2])smem;              // 17920 B
    short (*Sb)[2][32][72] = (short (*)[2][32][72])(smem + 17920); // 18432 B
    #pragma unroll
    for (int ct = 0; ct < 2; ++ct)
        #pragma unroll
        for (int r = 0; r < 4; ++r) {
            int n = (w << 4) + kq * 4 + r;
            int c = ct * 16 + l15;
            *(float2*)&P2[n][c][0] = make_float2(Pre_acc[ct][r], Pim_acc[ct][r]);
        }
    __syncthreads();

    // ---- scan (lane = n); waves duplicate, wave w stages its c-range ----
    {
        int n = lane;
        float sr = 0.f, si = 0.f;
        for (int c = 0; c < NC; ++c) {
            if ((c >> 3) == w) {
                short hr = bf16hi(sr); short lr = bf16hi(sr - bf16f(hr));
                short hi2 = bf16hi(si); short li = bf16hi(si - bf16f(hi2));
                Sb[0][0][c][n] = hr;  Sb[1][0][c][n] = lr;
                Sb[0][1][c][n] = hi2; Sb[1][1][c][n] = li;
            }
            float2 pv = *(float2*)&P2[n][c][0];
            float nsr = fmaf(a64r, sr, fmaf(-a64i, si, pv.x));
            float nsi = fmaf(a64i, sr, fmaf(a64r, si, pv.y));
            sr = nsr; si = nsi;
        }
    }
    __syncthreads();

    // ---- set 2: Y = [T|Gre|-Gim] * [U;Sre;Sim] ----
    f32x4 Yacc[2] = {{0.f,0.f,0.f,0.f},{0.f,0.f,0.f,0.f}};
    #pragma unroll
    for (int kt = 0; kt < 6; ++kt) {
        #pragma unroll
        for (int ct = 0; ct < 2; ++ct) {
            short8 bhf, blf;
            if (kt < 2) { bhf = Uh[kt][ct]; blf = Ul[kt][ct]; }
            else {
                int q2 = kt - 2, reim = q2 >> 1;
                int nb = (q2 & 1) * 32 + kq * 8;
                int c  = ct * 16 + l15;
                bhf = *(const short8*)&Sb[0][reim][c][nb];
                blf = *(const short8*)&Sb[1][reim][c][nb];
            }
            Yacc[ct] = MFMA16(A2f[kt], bhf, Yacc[ct], 0, 0, 0);
            Yacc[ct] = MFMA16(A2f[kt], blf, Yacc[ct], 0, 0, 0);
        }
    }
    // Y -> LDS (P2 region, stride 70 floats; disjoint from Sb still being read)
    float* Yl = (float*)smem;
    #pragma unroll
    for (int ct = 0; ct < 2; ++ct)
        #pragma unroll
        for (int r = 0; r < 4; ++r) {
            int j = (w << 4) + kq * 4 + r;
            int c = ct * 16 + l15;
            Yl[j * 70 + c] = Yacc[ct][r];
        }
    __syncthreads();

    // ---- epilogue: exact GELU (D*u already inside Y via T diagonal) ----
    #pragma unroll
    for (int i = 0; i < 8; ++i) {
        int c = (w << 3) + i;
        float y = Yl[lane * 70 + c];
        float g = 0.5f * y * (1.f + erff(y * 0.70710678118654752f));
        ypre[(size_t)bh * Ln + c * 64 + lane] = g;
    }
}

// ---------------------------------------------------------------------------
// K2: LayerNorm over H; float4 global I/O, transposed LDS tile. (unchanged)
// ---------------------------------------------------------------------------
__global__ __launch_bounds__(256)
void k_ln(const float* __restrict__ ypre, const float* __restrict__ gamma,
          const float* __restrict__ beta, float* __restrict__ out)
{
    __shared__ float tile[32][260];
    int b  = blockIdx.y;
    int l0 = blockIdx.x << 5;
    int t  = threadIdx.x;

    #pragma unroll
    for (int i = 0; i < 8; ++i) {
        int idx = (i << 8) + t;
        int hh  = idx >> 3, lo4 = idx & 7;
        float4 v = *(const float4*)&ypre[((size_t)b * Hn + hh) * Ln + l0 + (lo4 << 2)];
        tile[(lo4 << 2) + 0][hh] = v.x;
        tile[(lo4 << 2) + 1][hh] = v.y;
        tile[(lo4 << 2) + 2][hh] = v.z;
        tile[(lo4 << 2) + 3][hh] = v.w;
    }
    __syncthreads();

    int wv = t >> 6, lane = t & 63;
    float4 g4 = *(const float4*)&gamma[lane << 2];
    float4 b4 = *(const float4*)&beta[lane << 2];
    #pragma unroll
    for (int k = 0; k < 8; ++k) {
        int l = (k << 2) | wv;
        float4 v = *(const float4*)&tile[l][lane << 2];
        float sum = (v.x + v.y) + (v.z + v.w);
        float sq  = fmaf(v.x, v.x, fmaf(v.y, v.y, fmaf(v.z, v.z, v.w * v.w)));
        #pragma unroll
        for (int off = 32; off; off >>= 1) {
            sum += __shfl_xor(sum, off);
            sq  += __shfl_xor(sq, off);
        }
        float mean = sum * (1.f / 256.f);
        float var  = sq * (1.f / 256.f) - mean * mean;
        float rs   = rsqrtf(var + 1e-5f);
        float4 o;
        o.x = (v.x - mean) * rs * g4.x + b4.x;
        o.y = (v.y - mean) * rs * g4.y + b4.y;
        o.z = (v.z - mean) * rs * g4.z + b4.z;
        o.w = (v.w - mean) * rs * g4.w + b4.w;
        *(float4*)&out[((size_t)b * Ln + l0 + l) * Hn + (lane << 2)] = o;
    }
}

// ---------------------------------------------------------------------------
extern "C" void kernel_launch(void* const* d_in, const int* in_sizes, int n_in,
                              void* d_out, int out_size, void* d_ws, size_t ws_size,
                              hipStream_t stream)
{
    const float* u     = (const float*)d_in[0];
    const float* lnr   = (const float*)d_in[1];
    const float* im    = (const float*)d_in[2];
    const float* Bre   = (const float*)d_in[3];
    const float* Bim   = (const float*)d_in[4];
    const float* Cre   = (const float*)d_in[5];
    const float* Cim   = (const float*)d_in[6];
    const float* Dp    = (const float*)d_in[7];
    const float* lstep = (const float*)d_in[8];
    const float* gam   = (const float*)d_in[9];
    const float* bet   = (const float*)d_in[10];
    float* out = (float*)d_out;

    // workspace carve: only ypre (B,H,L) = 8 MB
    float* ypre = (float*)d_ws;

    k_s4d<<<Bn * Hn, 256, 0, stream>>>(u, lnr, im, Bre, Bim, Cre, Cim, lstep, Dp, ypre);
    k_ln<<<dim3(Ln / 32, Bn), 256, 0, stream>>>(ypre, gam, bet, out);
}

// Round 3
// 101.977 us; speedup vs baseline: 1.0356x; 1.0356x over previous
//
#include <hip/hip_runtime.h>
#include <hip/hip_bf16.h>
#include <math.h>

// Problem constants
#define Hn 256
#define Nn 64
#define Bn 4
#define Ln 2048
#define NC 32      // chunks per sequence

typedef __attribute__((ext_vector_type(8))) short short8;
typedef __attribute__((ext_vector_type(4))) float f32x4;

#define MFMA16 __builtin_amdgcn_mfma_f32_16x16x32_bf16

__device__ inline short bf16hi(float x) {
    union { __hip_bfloat16 b; unsigned short u; } cv;
    cv.b = __float2bfloat16(x);
    return (short)cv.u;
}
__device__ inline float bf16f(short s) {
    union { __hip_bfloat16 b; unsigned short u; } cv;
    cv.u = (unsigned short)s;
    return __bfloat162float(cv.b);
}

// complex square in place
#define CSQ(r, i) { float _nr = (r)*(r) - (i)*(i); (i) = 2.f*(r)*(i); (r) = _nr; }

// ---------------------------------------------------------------------------
// K1: one block per (b,h), fused gather/precompute/MFMA-scan/GELU.
// XCD-aware block->(b,h) remap: blockIdx -> XCD is round-robin (bid % 8, 8
// XCDs with private L2). We assign each XCD a contiguous 32-h band so every
// 64B line of u (16 consecutive h) is consumed by blocks on ONE XCD:
//   xcd = bid % 8; slot = bid / 8; h = xcd*32 + (slot & 31); b = slot >> 5.
// This cuts the scattered u-gather's HBM fetch from ~8x overfetch (~64 MB)
// to ~1x (8 MB). Bijective; ypre is indexed by the true (b,h).
// ---------------------------------------------------------------------------
__global__ __launch_bounds__(256, 4)
void k_s4d(const float* __restrict__ u,
           const float* __restrict__ lnr, const float* __restrict__ imv,
           const float* __restrict__ Bre, const float* __restrict__ Bim,
           const float* __restrict__ Cre, const float* __restrict__ Cim,
           const float* __restrict__ lstep, const float* __restrict__ Dp,
           float* __restrict__ ypre)
{
    __shared__ __align__(16) char smem[36864];

    const int bid  = blockIdx.x;
    const int xcd  = bid & 7;
    const int slot = bid >> 3;
    const int h    = (xcd << 5) + (slot & 31);
    const int b    = slot >> 5;
    const int bh   = (b << 8) + h;       // true (b,h) index for ypre
    const int tid  = threadIdx.x;
    const int lane = tid & 63;
    const int w    = __builtin_amdgcn_readfirstlane(tid >> 6);
    const int l15  = lane & 15;
    const int kq   = lane >> 4;
    const int mrow = (w << 4) + l15;

    // ---- P0: gather u[b,:,h] into padded LDS (us[c*68 + t], 2-way banks) ----
    float* us = (float*)smem;           // 32*68 = 2176 floats (8704 B)
    {
        const float* ucol = u + (size_t)b * Ln * Hn + h;
        #pragma unroll
        for (int i = 0; i < 8; ++i) {
            int l = tid + (i << 8);
            us[(l >> 6) * 68 + (l & 63)] = ucol[(size_t)l * Hn];
        }
    }

    // ---- per-lane (n = lane) parameters, duplicated across waves ----
    float st  = fminf(fmaxf(expf(lstep[h]), 1e-5f), 1.0f);
    float lam = -expf(lnr[lane]);
    float er  = expf(st * lam);
    float smv = st * imv[lane];
    float ar  = er * cosf(smv);
    float ai  = er * sinf(smv);
    float bre = Bre[h * Nn + lane] * st;
    float bim = Bim[h * Nn + lane] * st;
    float crr = Cre[h * Nn + lane];
    float cii = Cim[h * Nn + lane];
    float cbr = crr * bre - cii * bim;
    float cbi = crr * bim + cii * bre;
    float Dval = Dp[h];

    // power ladder: a^16, a^32, a^48, a^64
    float a16r = ar, a16i = ai;
    CSQ(a16r, a16i); CSQ(a16r, a16i); CSQ(a16r, a16i); CSQ(a16r, a16i);
    float a32r = a16r, a32i = a16i; CSQ(a32r, a32i);
    float a48r = a32r * a16r - a32i * a16i;
    float a48i = a32r * a16i + a32i * a16r;
    float a64r = a32r, a64i = a32i; CSQ(a64r, a64i);

    __syncthreads();

    // ---- U fragments from us (bf16 hi/lo) ----
    short8 Uh[2][2], Ul[2][2];             // [kt][ct]
    #pragma unroll
    for (int kt = 0; kt < 2; ++kt)
        #pragma unroll
        for (int ct = 0; ct < 2; ++ct) {
            int c = ct * 16 + l15;
            const float* up = &us[c * 68 + kt * 32 + kq * 8];
            float4 f0 = *(const float4*)up;
            float4 f1 = *(const float4*)(up + 4);
            float xv[8] = {f0.x, f0.y, f0.z, f0.w, f1.x, f1.y, f1.z, f1.w};
            union { short s[8]; short8 v; } hh, ll;
            #pragma unroll
            for (int j = 0; j < 8; ++j) {
                short hs = bf16hi(xv[j]);
                hh.s[j] = hs;
                ll.s[j] = bf16hi(xv[j] - bf16f(hs));
            }
            Uh[kt][ct] = hh.v;
            Ul[kt][ct] = ll.v;
        }

    __syncthreads();   // us dead; shA may now overwrite it

    // ---- P1a: Apow[n][t] = a_n^(63-t); wave w covers powers 16w..16w+15 ----
    float (*shA)[64][66] = (float (*)[64][66])smem;   // 33792 B
    float* cbrL = (float*)(smem + 33792);             // 64 f
    float* kb   = (float*)(smem + 34048);             // 128 f
    {
        float pr = 1.f, pi = 0.f;
        if (w == 1)      { pr = a16r; pi = a16i; }
        else if (w == 2) { pr = a32r; pi = a32i; }
        else if (w == 3) { pr = a48r; pi = a48i; }
        for (int i = 0; i < 16; ++i) {
            int t = 63 - ((w << 4) + i);
            shA[0][lane][t] = pr;
            shA[1][lane][t] = pi;
            float nr = pr * ar - pi * ai; pi = pr * ai + pi * ar; pr = nr;
        }
    }
    __syncthreads();

    // A1 fragments straight to registers (producer == consumer thread)
    short8 A1f[2][2];                      // [re/im][kt]
    #pragma unroll
    for (int cm = 0; cm < 2; ++cm)
        #pragma unroll
        for (int kt = 0; kt < 2; ++kt) {
            union { short s[8]; short8 v; } uh;
            #pragma unroll
            for (int j = 0; j < 8; ++j)
                uh.s[j] = bf16hi(shA[cm][mrow][kt * 32 + kq * 8 + j]);
            A1f[cm][kt] = uh.v;
        }
    __syncthreads();

    // ---- P1b: G[j][n] = CB_n a_n^(j+1); wave w covers j = 16w..16w+15 ----
    {
        float Pr, Pi;
        if (w == 0)      { Pr = ar; Pi = ai; }
        else if (w == 1) { Pr = a16r * ar - a16i * ai; Pi = a16r * ai + a16i * ar; }
        else if (w == 2) { Pr = a32r * ar - a32i * ai; Pi = a32r * ai + a32i * ar; }
        else             { Pr = a48r * ar - a48i * ai; Pi = a48r * ai + a48i * ar; }
        if (tid < 64) cbrL[lane] = cbr;
        for (int i = 0; i < 16; ++i) {
            int j = (w << 4) + i;
            shA[0][j][lane] = cbr * Pr - cbi * Pi;
            shA[1][j][lane] = cbr * Pi + cbi * Pr;
            float nr = Pr * ar - Pi * ai; Pi = Pr * ai + Pi * ar; Pr = nr;
        }
    }
    __syncthreads();

    // Krow -> kb (zero-padded low half); D folded into Krow[0] (T diagonal)
    if (tid < 64) kb[tid] = 0.f;
    else if (tid < 128) {
        int t2 = tid - 64;
        float s = 0.f;
        if (t2 == 0) { for (int n2 = 0; n2 < 64; ++n2) s += cbrL[n2]; s += Dval; }
        else         { for (int n2 = 0; n2 < 64; ++n2) s += shA[0][t2 - 1][n2]; }
        kb[tid] = s;
    }
    __syncthreads();

    // A2 fragments: [T | Gre | -Gim] rows mrow, straight to registers
    short8 A2f[6];
    #pragma unroll
    for (int kt = 0; kt < 6; ++kt) {
        union { short s[8]; short8 v; } uh;
        #pragma unroll
        for (int j = 0; j < 8; ++j) {
            float x;
            if (kt < 2) {
                int kk = kt * 32 + kq * 8 + j;           // column m of T
                x = kb[64 + mrow - kk];                   // T[j][m] = Krow[j-m]
            } else {
                int q2 = kt - 2;
                int nn = (q2 & 1) * 32 + kq * 8 + j;
                x = (q2 >> 1) ? -shA[1][mrow][nn] : shA[0][mrow][nn];
            }
            uh.s[j] = bf16hi(x);
        }
        A2f[kt] = uh.v;
    }
    __syncthreads();   // shA/kb dead; P2/Sb may now overwrite

    // ---- set 1: P = Apow * U ----
    f32x4 Pre_acc[2] = {{0.f,0.f,0.f,0.f},{0.f,0.f,0.f,0.f}};
    f32x4 Pim_acc[2] = {{0.f,0.f,0.f,0.f},{0.f,0.f,0.f,0.f}};
    #pragma unroll
    for (int kt = 0; kt < 2; ++kt) {
        #pragma unroll
        for (int ct = 0; ct < 2; ++ct) {
            Pre_acc[ct] = MFMA16(A1f[0][kt], Uh[kt][ct], Pre_acc[ct], 0, 0, 0);
            Pre_acc[ct] = MFMA16(A1f[0][kt], Ul[kt][ct], Pre_acc[ct], 0, 0, 0);
            Pim_acc[ct] = MFMA16(A1f[1][kt], Uh[kt][ct], Pim_acc[ct], 0, 0, 0);
            Pim_acc[ct] = MFMA16(A1f[1][kt], Ul[kt][ct], Pim_acc[ct], 0, 0, 0);
        }
    }
    float (*P2)[35][2]     = (float (*)[35][2])smem;              // 17920 B
    short (*Sb)[2][32][72] = (short (*)[2][32][72])(smem + 17920); // 18432 B
    #pragma unroll
    for (int ct = 0; ct < 2; ++ct)
        #pragma unroll
        for (int r = 0; r < 4; ++r) {
            int n = (w << 4) + kq * 4 + r;
            int c = ct * 16 + l15;
            *(float2*)&P2[n][c][0] = make_float2(Pre_acc[ct][r], Pim_acc[ct][r]);
        }
    __syncthreads();

    // ---- scan (lane = n); waves duplicate, wave w stages its c-range ----
    {
        int n = lane;
        float sr = 0.f, si = 0.f;
        for (int c = 0; c < NC; ++c) {
            if ((c >> 3) == w) {
                short hr = bf16hi(sr); short lr = bf16hi(sr - bf16f(hr));
                short hi2 = bf16hi(si); short li = bf16hi(si - bf16f(hi2));
                Sb[0][0][c][n] = hr;  Sb[1][0][c][n] = lr;
                Sb[0][1][c][n] = hi2; Sb[1][1][c][n] = li;
            }
            float2 pv = *(float2*)&P2[n][c][0];
            float nsr = fmaf(a64r, sr, fmaf(-a64i, si, pv.x));
            float nsi = fmaf(a64i, sr, fmaf(a64r, si, pv.y));
            sr = nsr; si = nsi;
        }
    }
    __syncthreads();

    // ---- set 2: Y = [T|Gre|-Gim] * [U;Sre;Sim] ----
    f32x4 Yacc[2] = {{0.f,0.f,0.f,0.f},{0.f,0.f,0.f,0.f}};
    #pragma unroll
    for (int kt = 0; kt < 6; ++kt) {
        #pragma unroll
        for (int ct = 0; ct < 2; ++ct) {
            short8 bhf, blf;
            if (kt < 2) { bhf = Uh[kt][ct]; blf = Ul[kt][ct]; }
            else {
                int q2 = kt - 2, reim = q2 >> 1;
                int nb = (q2 & 1) * 32 + kq * 8;
                int c  = ct * 16 + l15;
                bhf = *(const short8*)&Sb[0][reim][c][nb];
                blf = *(const short8*)&Sb[1][reim][c][nb];
            }
            Yacc[ct] = MFMA16(A2f[kt], bhf, Yacc[ct], 0, 0, 0);
            Yacc[ct] = MFMA16(A2f[kt], blf, Yacc[ct], 0, 0, 0);
        }
    }
    // Y -> LDS (P2 region, stride 70 floats; disjoint from Sb still being read)
    float* Yl = (float*)smem;
    #pragma unroll
    for (int ct = 0; ct < 2; ++ct)
        #pragma unroll
        for (int r = 0; r < 4; ++r) {
            int j = (w << 4) + kq * 4 + r;
            int c = ct * 16 + l15;
            Yl[j * 70 + c] = Yacc[ct][r];
        }
    __syncthreads();

    // ---- epilogue: exact GELU (D*u already inside Y via T diagonal) ----
    #pragma unroll
    for (int i = 0; i < 8; ++i) {
        int c = (w << 3) + i;
        float y = Yl[lane * 70 + c];
        float g = 0.5f * y * (1.f + erff(y * 0.70710678118654752f));
        ypre[(size_t)bh * Ln + c * 64 + lane] = g;
    }
}

// ---------------------------------------------------------------------------
// K2: LayerNorm over H; float4 global I/O, transposed LDS tile. (unchanged)
// ---------------------------------------------------------------------------
__global__ __launch_bounds__(256)
void k_ln(const float* __restrict__ ypre, const float* __restrict__ gamma,
          const float* __restrict__ beta, float* __restrict__ out)
{
    __shared__ float tile[32][260];
    int b  = blockIdx.y;
    int l0 = blockIdx.x << 5;
    int t  = threadIdx.x;

    #pragma unroll
    for (int i = 0; i < 8; ++i) {
        int idx = (i << 8) + t;
        int hh  = idx >> 3, lo4 = idx & 7;
        float4 v = *(const float4*)&ypre[((size_t)b * Hn + hh) * Ln + l0 + (lo4 << 2)];
        tile[(lo4 << 2) + 0][hh] = v.x;
        tile[(lo4 << 2) + 1][hh] = v.y;
        tile[(lo4 << 2) + 2][hh] = v.z;
        tile[(lo4 << 2) + 3][hh] = v.w;
    }
    __syncthreads();

    int wv = t >> 6, lane = t & 63;
    float4 g4 = *(const float4*)&gamma[lane << 2];
    float4 b4 = *(const float4*)&beta[lane << 2];
    #pragma unroll
    for (int k = 0; k < 8; ++k) {
        int l = (k << 2) | wv;
        float4 v = *(const float4*)&tile[l][lane << 2];
        float sum = (v.x + v.y) + (v.z + v.w);
        float sq  = fmaf(v.x, v.x, fmaf(v.y, v.y, fmaf(v.z, v.z, v.w * v.w)));
        #pragma unroll
        for (int off = 32; off; off >>= 1) {
            sum += __shfl_xor(sum, off);
            sq  += __shfl_xor(sq, off);
        }
        float mean = sum * (1.f / 256.f);
        float var  = sq * (1.f / 256.f) - mean * mean;
        float rs   = rsqrtf(var + 1e-5f);
        float4 o;
        o.x = (v.x - mean) * rs * g4.x + b4.x;
        o.y = (v.y - mean) * rs * g4.y + b4.y;
        o.z = (v.z - mean) * rs * g4.z + b4.z;
        o.w = (v.w - mean) * rs * g4.w + b4.w;
        *(float4*)&out[((size_t)b * Ln + l0 + l) * Hn + (lane << 2)] = o;
    }
}

// ---------------------------------------------------------------------------
extern "C" void kernel_launch(void* const* d_in, const int* in_sizes, int n_in,
                              void* d_out, int out_size, void* d_ws, size_t ws_size,
                              hipStream_t stream)
{
    const float* u     = (const float*)d_in[0];
    const float* lnr   = (const float*)d_in[1];
    const float* im    = (const float*)d_in[2];
    const float* Bre   = (const float*)d_in[3];
    const float* Bim   = (const float*)d_in[4];
    const float* Cre   = (const float*)d_in[5];
    const float* Cim   = (const float*)d_in[6];
    const float* Dp    = (const float*)d_in[7];
    const float* lstep = (const float*)d_in[8];
    const float* gam   = (const float*)d_in[9];
    const float* bet   = (const float*)d_in[10];
    float* out = (float*)d_out;

    // workspace carve: only ypre (B,H,L) = 8 MB
    float* ypre = (float*)d_ws;

    k_s4d<<<Bn * Hn, 256, 0, stream>>>(u, lnr, im, Bre, Bim, Cre, Cim, lstep, Dp, ypre);
    k_ln<<<dim3(Ln / 32, Bn), 256, 0, stream>>>(ypre, gam, bet, out);
}

// Round 4
// 100.045 us; speedup vs baseline: 1.0556x; 1.0193x over previous
//
#include <hip/hip_runtime.h>
#include <hip/hip_bf16.h>
#include <math.h>

// Problem constants
#define Hn 256
#define Nn 64
#define Bn 4
#define Ln 2048
#define NC 32      // chunks per sequence

typedef __attribute__((ext_vector_type(8))) short short8;
typedef __attribute__((ext_vector_type(4))) float f32x4;

#define MFMA16 __builtin_amdgcn_mfma_f32_16x16x32_bf16

__device__ inline short bf16hi(float x) {
    union { __hip_bfloat16 b; unsigned short u; } cv;
    cv.b = __float2bfloat16(x);
    return (short)cv.u;
}
__device__ inline float bf16f(short s) {
    union { __hip_bfloat16 b; unsigned short u; } cv;
    cv.u = (unsigned short)s;
    return __bfloat162float(cv.b);
}

// complex square in place
#define CSQ(r, i) { float _nr = (r)*(r) - (i)*(i); (i) = 2.f*(r)*(i); (r) = _nr; }

// ---------------------------------------------------------------------------
// K1: one block per (b,h), fused gather/precompute/MFMA-scan/GELU.
// XCD-aware block->(b,h) remap (bid%8 -> XCD round-robin; each XCD gets a
// contiguous 32-h band so every 64B line of u is consumed on ONE XCD's L2).
// Krow reduction parallelized across all 4 waves (was serial-64 in 1 wave).
// ---------------------------------------------------------------------------
__global__ __launch_bounds__(256, 4)
void k_s4d(const float* __restrict__ u,
           const float* __restrict__ lnr, const float* __restrict__ imv,
           const float* __restrict__ Bre, const float* __restrict__ Bim,
           const float* __restrict__ Cre, const float* __restrict__ Cim,
           const float* __restrict__ lstep, const float* __restrict__ Dp,
           float* __restrict__ ypre)
{
    __shared__ __align__(16) char smem[36864];

    const int bid  = blockIdx.x;
    const int xcd  = bid & 7;
    const int slot = bid >> 3;
    const int h    = (xcd << 5) + (slot & 31);
    const int b    = slot >> 5;
    const int bh   = (b << 8) + h;       // true (b,h) index for ypre
    const int tid  = threadIdx.x;
    const int lane = tid & 63;
    const int w    = __builtin_amdgcn_readfirstlane(tid >> 6);
    const int l15  = lane & 15;
    const int kq   = lane >> 4;
    const int mrow = (w << 4) + l15;

    // ---- P0: gather u[b,:,h] into padded LDS (us[c*68 + t], 2-way banks) ----
    float* us = (float*)smem;           // 32*68 = 2176 floats (8704 B)
    {
        const float* ucol = u + (size_t)b * Ln * Hn + h;
        #pragma unroll
        for (int i = 0; i < 8; ++i) {
            int l = tid + (i << 8);
            us[(l >> 6) * 68 + (l & 63)] = ucol[(size_t)l * Hn];
        }
    }

    // ---- per-lane (n = lane) parameters, duplicated across waves ----
    float st  = fminf(fmaxf(expf(lstep[h]), 1e-5f), 1.0f);
    float lam = -expf(lnr[lane]);
    float er  = expf(st * lam);
    float smv = st * imv[lane];
    float ar  = er * cosf(smv);
    float ai  = er * sinf(smv);
    float bre = Bre[h * Nn + lane] * st;
    float bim = Bim[h * Nn + lane] * st;
    float crr = Cre[h * Nn + lane];
    float cii = Cim[h * Nn + lane];
    float cbr = crr * bre - cii * bim;
    float cbi = crr * bim + cii * bre;
    float Dval = Dp[h];

    // power ladder: a^16, a^32, a^48, a^64
    float a16r = ar, a16i = ai;
    CSQ(a16r, a16i); CSQ(a16r, a16i); CSQ(a16r, a16i); CSQ(a16r, a16i);
    float a32r = a16r, a32i = a16i; CSQ(a32r, a32i);
    float a48r = a32r * a16r - a32i * a16i;
    float a48i = a32r * a16i + a32i * a16r;
    float a64r = a32r, a64i = a32i; CSQ(a64r, a64i);

    __syncthreads();

    // ---- U fragments from us (bf16 hi/lo) ----
    short8 Uh[2][2], Ul[2][2];             // [kt][ct]
    #pragma unroll
    for (int kt = 0; kt < 2; ++kt)
        #pragma unroll
        for (int ct = 0; ct < 2; ++ct) {
            int c = ct * 16 + l15;
            const float* up = &us[c * 68 + kt * 32 + kq * 8];
            float4 f0 = *(const float4*)up;
            float4 f1 = *(const float4*)(up + 4);
            float xv[8] = {f0.x, f0.y, f0.z, f0.w, f1.x, f1.y, f1.z, f1.w};
            union { short s[8]; short8 v; } hh, ll;
            #pragma unroll
            for (int j = 0; j < 8; ++j) {
                short hs = bf16hi(xv[j]);
                hh.s[j] = hs;
                ll.s[j] = bf16hi(xv[j] - bf16f(hs));
            }
            Uh[kt][ct] = hh.v;
            Ul[kt][ct] = ll.v;
        }

    __syncthreads();   // us dead; shA may now overwrite it

    // ---- P1a: Apow[n][t] = a_n^(63-t); wave w covers powers 16w..16w+15 ----
    float (*shA)[64][66] = (float (*)[64][66])smem;   // 33792 B
    float* cbrL = (float*)(smem + 33792);             // 64 f   (ends 34048)
    float* kb   = (float*)(smem + 34048);             // 128 f  (ends 34560)
    float* part = (float*)(smem + 34560);             // 256 f  (ends 35584)
    {
        float pr = 1.f, pi = 0.f;
        if (w == 1)      { pr = a16r; pi = a16i; }
        else if (w == 2) { pr = a32r; pi = a32i; }
        else if (w == 3) { pr = a48r; pi = a48i; }
        for (int i = 0; i < 16; ++i) {
            int t = 63 - ((w << 4) + i);
            shA[0][lane][t] = pr;
            shA[1][lane][t] = pi;
            float nr = pr * ar - pi * ai; pi = pr * ai + pi * ar; pr = nr;
        }
    }
    __syncthreads();

    // A1 fragments straight to registers (producer == consumer thread)
    short8 A1f[2][2];                      // [re/im][kt]
    #pragma unroll
    for (int cm = 0; cm < 2; ++cm)
        #pragma unroll
        for (int kt = 0; kt < 2; ++kt) {
            union { short s[8]; short8 v; } uh;
            #pragma unroll
            for (int j = 0; j < 8; ++j)
                uh.s[j] = bf16hi(shA[cm][mrow][kt * 32 + kq * 8 + j]);
            A1f[cm][kt] = uh.v;
        }
    __syncthreads();

    // ---- P1b: G[j][n] = CB_n a_n^(j+1); wave w covers j = 16w..16w+15 ----
    {
        float Pr, Pi;
        if (w == 0)      { Pr = ar; Pi = ai; }
        else if (w == 1) { Pr = a16r * ar - a16i * ai; Pi = a16r * ai + a16i * ar; }
        else if (w == 2) { Pr = a32r * ar - a32i * ai; Pi = a32r * ai + a32i * ar; }
        else             { Pr = a48r * ar - a48i * ai; Pi = a48r * ai + a48i * ar; }
        if (tid < 64) cbrL[lane] = cbr;
        for (int i = 0; i < 16; ++i) {
            int j = (w << 4) + i;
            shA[0][j][lane] = cbr * Pr - cbi * Pi;
            shA[1][j][lane] = cbr * Pi + cbi * Pr;
            float nr = Pr * ar - Pi * ai; Pi = Pr * ai + Pi * ar; Pr = nr;
        }
    }
    __syncthreads();

    // Krow partials: all 256 threads; thread (q=w, t2=lane) sums its quarter.
    // Row t2 of the virtual matrix X: X[0][n]=cbrL[n], X[t2][n]=shA[0][t2-1][n].
    {
        int t2 = lane;
        float s = 0.f;
        #pragma unroll 4
        for (int i = 0; i < 16; ++i) {
            int n2 = (w << 4) + i;
            s += (t2 == 0) ? cbrL[n2] : shA[0][t2 - 1][n2];
        }
        part[(w << 6) + t2] = s;
    }
    __syncthreads();
    // combine -> kb (zero-padded low half); D folded into Krow[0] (T diagonal)
    if (tid < 64) kb[tid] = 0.f;
    else if (tid < 128) {
        int t2 = tid - 64;
        float s = ((part[t2] + part[64 + t2]) + (part[128 + t2] + part[192 + t2]));
        if (t2 == 0) s += Dval;
        kb[tid] = s;
    }
    __syncthreads();

    // A2 fragments: [T | Gre | -Gim] rows mrow, straight to registers
    short8 A2f[6];
    #pragma unroll
    for (int kt = 0; kt < 6; ++kt) {
        union { short s[8]; short8 v; } uh;
        #pragma unroll
        for (int j = 0; j < 8; ++j) {
            float x;
            if (kt < 2) {
                int kk = kt * 32 + kq * 8 + j;           // column m of T
                x = kb[64 + mrow - kk];                   // T[j][m] = Krow[j-m]
            } else {
                int q2 = kt - 2;
                int nn = (q2 & 1) * 32 + kq * 8 + j;
                x = (q2 >> 1) ? -shA[1][mrow][nn] : shA[0][mrow][nn];
            }
            uh.s[j] = bf16hi(x);
        }
        A2f[kt] = uh.v;
    }
    __syncthreads();   // shA/kb dead; P2/Sb may now overwrite

    // ---- set 1: P = Apow * U ----
    f32x4 Pre_acc[2] = {{0.f,0.f,0.f,0.f},{0.f,0.f,0.f,0.f}};
    f32x4 Pim_acc[2] = {{0.f,0.f,0.f,0.f},{0.f,0.f,0.f,0.f}};
    #pragma unroll
    for (int kt = 0; kt < 2; ++kt) {
        #pragma unroll
        for (int ct = 0; ct < 2; ++ct) {
            Pre_acc[ct] = MFMA16(A1f[0][kt], Uh[kt][ct], Pre_acc[ct], 0, 0, 0);
            Pre_acc[ct] = MFMA16(A1f[0][kt], Ul[kt][ct], Pre_acc[ct], 0, 0, 0);
            Pim_acc[ct] = MFMA16(A1f[1][kt], Uh[kt][ct], Pim_acc[ct], 0, 0, 0);
            Pim_acc[ct] = MFMA16(A1f[1][kt], Ul[kt][ct], Pim_acc[ct], 0, 0, 0);
        }
    }
    float (*P2)[35][2]     = (float (*)[35][2])smem;              // 17920 B
    short (*Sb)[2][32][72] = (short (*)[2][32][72])(smem + 17920); // 18432 B
    #pragma unroll
    for (int ct = 0; ct < 2; ++ct)
        #pragma unroll
        for (int r = 0; r < 4; ++r) {
            int n = (w << 4) + kq * 4 + r;
            int c = ct * 16 + l15;
            *(float2*)&P2[n][c][0] = make_float2(Pre_acc[ct][r], Pim_acc[ct][r]);
        }
    __syncthreads();

    // ---- scan (lane = n); waves duplicate, wave w stages its c-range ----
    {
        int n = lane;
        float sr = 0.f, si = 0.f;
        for (int c = 0; c < NC; ++c) {
            if ((c >> 3) == w) {
                short hr = bf16hi(sr); short lr = bf16hi(sr - bf16f(hr));
                short hi2 = bf16hi(si); short li = bf16hi(si - bf16f(hi2));
                Sb[0][0][c][n] = hr;  Sb[1][0][c][n] = lr;
                Sb[0][1][c][n] = hi2; Sb[1][1][c][n] = li;
            }
            float2 pv = *(float2*)&P2[n][c][0];
            float nsr = fmaf(a64r, sr, fmaf(-a64i, si, pv.x));
            float nsi = fmaf(a64i, sr, fmaf(a64r, si, pv.y));
            sr = nsr; si = nsi;
        }
    }
    __syncthreads();

    // ---- set 2: Y = [T|Gre|-Gim] * [U;Sre;Sim] ----
    f32x4 Yacc[2] = {{0.f,0.f,0.f,0.f},{0.f,0.f,0.f,0.f}};
    #pragma unroll
    for (int kt = 0; kt < 6; ++kt) {
        #pragma unroll
        for (int ct = 0; ct < 2; ++ct) {
            short8 bhf, blf;
            if (kt < 2) { bhf = Uh[kt][ct]; blf = Ul[kt][ct]; }
            else {
                int q2 = kt - 2, reim = q2 >> 1;
                int nb = (q2 & 1) * 32 + kq * 8;
                int c  = ct * 16 + l15;
                bhf = *(const short8*)&Sb[0][reim][c][nb];
                blf = *(const short8*)&Sb[1][reim][c][nb];
            }
            Yacc[ct] = MFMA16(A2f[kt], bhf, Yacc[ct], 0, 0, 0);
            Yacc[ct] = MFMA16(A2f[kt], blf, Yacc[ct], 0, 0, 0);
        }
    }
    // Y -> LDS (P2 region, stride 70 floats; disjoint from Sb still being read)
    float* Yl = (float*)smem;
    #pragma unroll
    for (int ct = 0; ct < 2; ++ct)
        #pragma unroll
        for (int r = 0; r < 4; ++r) {
            int j = (w << 4) + kq * 4 + r;
            int c = ct * 16 + l15;
            Yl[j * 70 + c] = Yacc[ct][r];
        }
    __syncthreads();

    // ---- epilogue: exact GELU (D*u already inside Y via T diagonal) ----
    #pragma unroll
    for (int i = 0; i < 8; ++i) {
        int c = (w << 3) + i;
        float y = Yl[lane * 70 + c];
        float g = 0.5f * y * (1.f + erff(y * 0.70710678118654752f));
        ypre[(size_t)bh * Ln + c * 64 + lane] = g;
    }
}

// ---------------------------------------------------------------------------
// K2: LayerNorm over H. Regridded: 512 blocks (16-l slabs) -> 2 blocks/CU,
// 8 waves/CU (was 1 block/CU, 4 waves) for latency hiding; 16-l slab keeps
// 100% of each 64B line on both the (B,H,L) read and (B,L,H) write.
// ---------------------------------------------------------------------------
__global__ __launch_bounds__(256)
void k_ln(const float* __restrict__ ypre, const float* __restrict__ gamma,
          const float* __restrict__ beta, float* __restrict__ out)
{
    __shared__ float tile[16][260];
    int b  = blockIdx.y;
    int l0 = blockIdx.x << 4;
    int t  = threadIdx.x;

    #pragma unroll
    for (int i = 0; i < 4; ++i) {
        int idx = (i << 8) + t;
        int hh  = idx >> 2, lo4 = idx & 3;
        float4 v = *(const float4*)&ypre[((size_t)b * Hn + hh) * Ln + l0 + (lo4 << 2)];
        tile[(lo4 << 2) + 0][hh] = v.x;
        tile[(lo4 << 2) + 1][hh] = v.y;
        tile[(lo4 << 2) + 2][hh] = v.z;
        tile[(lo4 << 2) + 3][hh] = v.w;
    }
    __syncthreads();

    int wv = t >> 6, lane = t & 63;
    float4 g4 = *(const float4*)&gamma[lane << 2];
    float4 b4 = *(const float4*)&beta[lane << 2];
    #pragma unroll
    for (int k = 0; k < 4; ++k) {
        int l = (k << 2) | wv;
        float4 v = *(const float4*)&tile[l][lane << 2];
        float sum = (v.x + v.y) + (v.z + v.w);
        float sq  = fmaf(v.x, v.x, fmaf(v.y, v.y, fmaf(v.z, v.z, v.w * v.w)));
        #pragma unroll
        for (int off = 32; off; off >>= 1) {
            sum += __shfl_xor(sum, off);
            sq  += __shfl_xor(sq, off);
        }
        float mean = sum * (1.f / 256.f);
        float var  = sq * (1.f / 256.f) - mean * mean;
        float rs   = rsqrtf(var + 1e-5f);
        float4 o;
        o.x = (v.x - mean) * rs * g4.x + b4.x;
        o.y = (v.y - mean) * rs * g4.y + b4.y;
        o.z = (v.z - mean) * rs * g4.z + b4.z;
        o.w = (v.w - mean) * rs * g4.w + b4.w;
        *(float4*)&out[((size_t)b * Ln + l0 + l) * Hn + (lane << 2)] = o;
    }
}

// ---------------------------------------------------------------------------
extern "C" void kernel_launch(void* const* d_in, const int* in_sizes, int n_in,
                              void* d_out, int out_size, void* d_ws, size_t ws_size,
                              hipStream_t stream)
{
    const float* u     = (const float*)d_in[0];
    const float* lnr   = (const float*)d_in[1];
    const float* im    = (const float*)d_in[2];
    const float* Bre   = (const float*)d_in[3];
    const float* Bim   = (const float*)d_in[4];
    const float* Cre   = (const float*)d_in[5];
    const float* Cim   = (const float*)d_in[6];
    const float* Dp    = (const float*)d_in[7];
    const float* lstep = (const float*)d_in[8];
    const float* gam   = (const float*)d_in[9];
    const float* bet   = (const float*)d_in[10];
    float* out = (float*)d_out;

    // workspace carve: only ypre (B,H,L) = 8 MB
    float* ypre = (float*)d_ws;

    k_s4d<<<Bn * Hn, 256, 0, stream>>>(u, lnr, im, Bre, Bim, Cre, Cim, lstep, Dp, ypre);
    k_ln<<<dim3(Ln / 16, Bn), 256, 0, stream>>>(ypre, gam, bet, out);
}